// Round 1
// baseline (18.548 us; speedup 1.0000x reference)
//
#include <hip/hip_runtime.h>

#define N_ROWS 16384
#define DIM 512
#define NBLOCKS 1024
#define CLAMP_MIN 1e-12f
#define CLAMP_MAX 1e12f

__global__ __launch_bounds__(256) void centerloss_partial(
    const float* __restrict__ features,
    const int* __restrict__ labels,
    const float* __restrict__ centers,
    float* __restrict__ partials)
{
    const int lane = threadIdx.x & 63;
    const int wave_in_block = threadIdx.x >> 6;      // 0..3
    const int waves_per_block = blockDim.x >> 6;     // 4
    const int global_wave = blockIdx.x * waves_per_block + wave_in_block;
    const int total_waves = gridDim.x * waves_per_block;

    float wsum = 0.f;

    for (int row = global_wave; row < N_ROWS; row += total_waves) {
        const int cls = labels[row * 2 + 1];         // labels[:, -1]
        const float4* __restrict__ f4 =
            reinterpret_cast<const float4*>(features + (size_t)row * DIM);
        const float4* __restrict__ c4 =
            reinterpret_cast<const float4*>(centers + (size_t)cls * DIM);

        // 512 floats = 128 float4 per row; 64 lanes x 2 coalesced loads
        float4 fa = f4[lane];
        float4 ca = c4[lane];
        float4 fb = f4[lane + 64];
        float4 cb = c4[lane + 64];

        float dx, acc = 0.f;
        dx = fa.x - ca.x; acc += dx * dx;
        dx = fa.y - ca.y; acc += dx * dx;
        dx = fa.z - ca.z; acc += dx * dx;
        dx = fa.w - ca.w; acc += dx * dx;
        dx = fb.x - cb.x; acc += dx * dx;
        dx = fb.y - cb.y; acc += dx * dx;
        dx = fb.z - cb.z; acc += dx * dx;
        dx = fb.w - cb.w; acc += dx * dx;

        // full butterfly reduce across 64 lanes -> all lanes hold row d2
        #pragma unroll
        for (int off = 1; off < 64; off <<= 1)
            acc += __shfl_xor(acc, off, 64);

        float d2 = fminf(fmaxf(acc, CLAMP_MIN), CLAMP_MAX);
        wsum += d2;
    }

    __shared__ float smem[8];
    if (lane == 0) smem[wave_in_block] = wsum;
    __syncthreads();
    if (threadIdx.x == 0) {
        float b = 0.f;
        for (int w = 0; w < waves_per_block; ++w) b += smem[w];
        partials[blockIdx.x] = b;
    }
}

__global__ __launch_bounds__(256) void centerloss_final(
    const float* __restrict__ partials, int n, float* __restrict__ out)
{
    float s = 0.f;
    for (int i = threadIdx.x; i < n; i += blockDim.x)
        s += partials[i];

    #pragma unroll
    for (int off = 1; off < 64; off <<= 1)
        s += __shfl_xor(s, off, 64);

    __shared__ float smem[8];
    const int lane = threadIdx.x & 63;
    const int wave = threadIdx.x >> 6;
    if (lane == 0) smem[wave] = s;
    __syncthreads();
    if (threadIdx.x == 0) {
        float t = 0.f;
        for (int w = 0; w < (int)(blockDim.x >> 6); ++w) t += smem[w];
        out[0] = t / (float)N_ROWS;
    }
}

extern "C" void kernel_launch(void* const* d_in, const int* in_sizes, int n_in,
                              void* d_out, int out_size, void* d_ws, size_t ws_size,
                              hipStream_t stream)
{
    const float* features = (const float*)d_in[0];
    const int*   labels   = (const int*)d_in[1];
    const float* centers  = (const float*)d_in[2];
    float* out = (float*)d_out;
    float* partials = (float*)d_ws;

    centerloss_partial<<<NBLOCKS, 256, 0, stream>>>(features, labels, centers, partials);
    centerloss_final<<<1, 256, 0, stream>>>(partials, NBLOCKS, out);
}